// Round 18
// baseline (67.313 us; speedup 1.0000x reference)
//
#include <hip/hip_runtime.h>
#include <math.h>

namespace {

constexpr int SEQ    = 4;
constexpr int WCHUNK = 64 * SEQ;   // 256 elements = one wave's chunk

// Per-wave LDS: gy 768 floats (3 KB) | ac 768 floats (3 KB) = 6 KB.
// Block = 2 independent waves -> 12 KB -> 13 blocks/CU = 26 waves/CU.
constexpr int WAVE_F = 1536;       // floats per wave
constexpr int AC_REL = 768;        // ac region offset within wave (floats)

struct V3 { float x, y, z; };
struct Q4 { float x, y, z, w; };
struct St { Q4 q; V3 s; V3 p; float T; float pad; }; // 48 B (aggs/k_pref)

__device__ __forceinline__ Q4 qmul(const Q4 a, const Q4 b) {
  Q4 r;
  r.x = a.w*b.x + b.w*a.x + a.y*b.z - a.z*b.y;
  r.y = a.w*b.y + b.w*a.y + a.z*b.x - a.x*b.z;
  r.z = a.w*b.z + b.w*a.z + a.x*b.y - a.y*b.x;
  r.w = a.w*b.w - a.x*b.x - a.y*b.y - a.z*b.z;
  return r;
}

__device__ __forceinline__ V3 qrot(const Q4 q, const V3 v) {
  float tx = q.y*v.z - q.z*v.y + q.w*v.x;
  float ty = q.z*v.x - q.x*v.z + q.w*v.y;
  float tz = q.x*v.y - q.y*v.x + q.w*v.z;
  V3 r;
  r.x = v.x + 2.0f*(q.y*tz - q.z*ty);
  r.y = v.y + 2.0f*(q.z*tx - q.x*tz);
  r.z = v.z + 2.0f*(q.x*ty - q.y*tx);
  return r;
}

__device__ __forceinline__ St combine(const St a, const St b) {
  St r;
  r.q = qmul(a.q, b.q);
  V3 rs = qrot(a.q, b.s);
  r.s.x = a.s.x + rs.x;
  r.s.y = a.s.y + rs.y;
  r.s.z = a.s.z + rs.z;
  V3 rp = qrot(a.q, b.p);
  r.p.x = a.p.x + a.s.x*b.T + rp.x;
  r.p.y = a.p.y + a.s.y*b.T + rp.y;
  r.p.z = a.p.z + a.s.z*b.T + rp.z;
  r.T = a.T + b.T;
  r.pad = 0.0f;
  return r;
}

__device__ __forceinline__ St identity_st() {
  St r;
  r.q = {0.0f, 0.0f, 0.0f, 1.0f};
  r.s = {0.0f, 0.0f, 0.0f};
  r.p = {0.0f, 0.0f, 0.0f};
  r.T = 0.0f; r.pad = 0.0f;
  return r;
}

// slim element: dr quaternion, s = qrot(dr, a)*dt, dt.  (e.p == e.s*dt/2
// implicitly.)  θ ≤ ~0.02: 2-term Taylor fp32-exact, no libm.
struct El { Q4 q; V3 s; float dt; };

__device__ __forceinline__ El elem_state(float dt, V3 w, V3 ac, Q4 gt) {
  float px = w.x*dt, py = w.y*dt, pz = w.z*dt;
  float t2 = px*px + py*py + pz*pz;                        // θ²
  float k  = 0.5f + t2*(-1.0f/48.0f  + t2*(1.0f/3840.0f)); // sin(θ/2)/θ
  float cw = 1.0f + t2*(-0.125f      + t2*(1.0f/384.0f));  // cos(θ/2)
  Q4 dr = { px*k, py*k, pz*k, cw };
  Q4 gi = { -gt.x, -gt.y, -gt.z, gt.w };
  V3 g  = { 0.0f, 0.0f, 9.81007f };
  V3 gr = qrot(gi, g);
  V3 a  = { ac.x - gr.x, ac.y - gr.y, ac.z - gr.z };
  V3 ra = qrot(dr, a);
  El e;
  e.q = dr;
  e.s = { ra.x*dt, ra.y*dt, ra.z*dt };
  e.dt = dt;
  return e;
}

__device__ __forceinline__ Q4 shfl_up_q(const Q4 v, int d) {
  return { __shfl_up(v.x,d), __shfl_up(v.y,d), __shfl_up(v.z,d), __shfl_up(v.w,d) };
}
__device__ __forceinline__ V3 shfl_up_v(const V3 v, int d) {
  return { __shfl_up(v.x,d), __shfl_up(v.y,d), __shfl_up(v.z,d) };
}

__device__ __forceinline__ St shfl_up_st(const St& v, int d) {
  St r;
  r.q.x = __shfl_up(v.q.x, d); r.q.y = __shfl_up(v.q.y, d);
  r.q.z = __shfl_up(v.q.z, d); r.q.w = __shfl_up(v.q.w, d);
  r.s.x = __shfl_up(v.s.x, d); r.s.y = __shfl_up(v.s.y, d);
  r.s.z = __shfl_up(v.s.z, d);
  r.p.x = __shfl_up(v.p.x, d); r.p.y = __shfl_up(v.p.y, d);
  r.p.z = __shfl_up(v.p.z, d);
  r.T   = __shfl_up(v.T, d);   r.pad = 0.0f;
  return r;
}

__device__ __forceinline__ St bcast_st(const St& v, int src) {
  St r;
  r.q.x = __shfl(v.q.x, src); r.q.y = __shfl(v.q.y, src);
  r.q.z = __shfl(v.q.z, src); r.q.w = __shfl(v.q.w, src);
  r.s.x = __shfl(v.s.x, src); r.s.y = __shfl(v.s.y, src);
  r.s.z = __shfl(v.s.z, src);
  r.p.x = __shfl(v.p.x, src); r.p.y = __shfl(v.p.y, src);
  r.p.z = __shfl(v.p.z, src);
  r.T   = __shfl(v.T, src);   r.pad = 0.0f;
  return r;
}

// Swizzle: XOR byte-addr bits 4-5 with bits 8-9 (involution, 16B-preserving,
// bijective per 256 B block). All region bases are 1024B-aligned so absolute
// and region-relative swizzles agree. LDS-read side (L4) + GLOBAL SOURCE
// side for global_load_lds (rule #21).
__device__ __forceinline__ int swz(int byteoff) {
  return byteoff ^ (((byteoff >> 8) & 3) << 4);
}
__device__ __forceinline__ float4& L4(float* lds, int fidx) {
  return *reinterpret_cast<float4*>(reinterpret_cast<char*>(lds) + swz(fidx << 2));
}

__device__ __forceinline__ void stage16(const void* gsrc, void* ldst) {
  __builtin_amdgcn_global_load_lds(
      (const __attribute__((address_space(1))) void*)gsrc,
      (__attribute__((address_space(3))) void*)ldst, 16, 0, 0);
}

struct Compressed { float cq[12]; float cs[12]; float cdt[4]; };
struct Seg { Q4 q; V3 s; V3 p; float T; };
struct ScanRes { Q4 qex, qin; V3 sex, sin; V3 pex, pin; float Tex, Tin; };

// Stage gy+ac for one wave (6 DMAs); gt and dt go direct to registers.
// Per-wave DMA readiness is a raw vmcnt(0) wait (wave-private LDS -> no
// block barrier needed; ds_read is a memory op so the "memory" clobber
// orders it after the wait).
__device__ __forceinline__ void stage_wave(float* lds, int wbB, int t,
    const float* gyp, const float* acp, size_t base) {
  const char* gy = (const char*)(gyp + base*3);
  const char* ac = (const char*)(acp + base*3);
  #pragma unroll
  for (int k = 0; k < 3; ++k) {
    int db = k*1024 + t*16;
    stage16(gy + swz(db), (char*)lds + wbB + k*1024);
    stage16(ac + swz(db), (char*)lds + wbB + 3072 + k*1024);
  }
}

// read 4 elements (gy/ac from staged LDS, gt from regs), build slim states
// + thread-local segment aggregate.
__device__ __forceinline__ Seg build_slim(float* lds, int wbF, int t,
                                          float4 dt4, const float4* gq4,
                                          Compressed& C) {
  float gy[12], ac[12];
  #pragma unroll
  for (int j = 0; j < 3; ++j) ((float4*)gy)[j] = L4(lds, wbF + 12*t + 4*j);
  #pragma unroll
  for (int j = 0; j < 3; ++j) ((float4*)ac)[j] = L4(lds, wbF + AC_REL + 12*t + 4*j);
  const float dtv[4] = {dt4.x, dt4.y, dt4.z, dt4.w};
  Seg s;
  #pragma unroll
  for (int i = 0; i < SEQ; ++i) {
    El e = elem_state(dtv[i],
               {gy[3*i], gy[3*i+1], gy[3*i+2]},
               {ac[3*i], ac[3*i+1], ac[3*i+2]},
               {gq4[i].x, gq4[i].y, gq4[i].z, gq4[i].w});
    C.cq[3*i] = e.q.x; C.cq[3*i+1] = e.q.y; C.cq[3*i+2] = e.q.z;
    C.cs[3*i] = e.s.x; C.cs[3*i+1] = e.s.y; C.cs[3*i+2] = e.s.z;
    C.cdt[i]  = e.dt;
    if (i == 0) {
      s.q = e.q; s.s = e.s;
      float h = 0.5f*e.dt;
      s.p = { e.s.x*h, e.s.y*h, e.s.z*h };
      s.T = e.dt;
    } else {
      V3 v = qrot(s.q, e.s);
      float h = 0.5f*e.dt;
      s.p.x += s.s.x*e.dt + v.x*h;
      s.p.y += s.s.y*e.dt + v.y*h;
      s.p.z += s.s.z*e.dt + v.z*h;
      s.s.x += v.x; s.s.y += v.y; s.s.z += v.z;
      s.q = qmul(s.q, e.q);
      s.T += e.dt;
    }
  }
  return s;
}

// split wave scan (order-preserving): quaternion scan + additive scans.
__device__ __forceinline__ ScanRes wave_split_scan(int t, const Seg& sg) {
  ScanRes r;
  Q4 qin = sg.q;
  #pragma unroll
  for (int d = 1; d < 64; d <<= 1) {
    Q4 o = shfl_up_q(qin, d);
    if (t >= d) qin = qmul(o, qin);
  }
  Q4 qex = shfl_up_q(qin, 1);
  if (t == 0) qex = {0.0f, 0.0f, 0.0f, 1.0f};
  V3 v = qrot(qex, sg.s);
  V3 sin_ = v;
  #pragma unroll
  for (int d = 1; d < 64; d <<= 1) {
    V3 o = shfl_up_v(sin_, d);
    if (t >= d) { sin_.x += o.x; sin_.y += o.y; sin_.z += o.z; }
  }
  V3 sex = shfl_up_v(sin_, 1);
  if (t == 0) sex = {0.0f, 0.0f, 0.0f};
  float Tin = sg.T;
  #pragma unroll
  for (int d = 1; d < 64; d <<= 1) {
    float o = __shfl_up(Tin, d);
    if (t >= d) Tin += o;
  }
  float Tex = __shfl_up(Tin, 1);
  if (t == 0) Tex = 0.0f;
  V3 w = qrot(qex, sg.p);
  V3 u = { w.x + sex.x*sg.T, w.y + sex.y*sg.T, w.z + sex.z*sg.T };
  V3 pin = u;
  #pragma unroll
  for (int d = 1; d < 64; d <<= 1) {
    V3 o = shfl_up_v(pin, d);
    if (t >= d) { pin.x += o.x; pin.y += o.y; pin.z += o.z; }
  }
  V3 pex = shfl_up_v(pin, 1);
  if (t == 0) pex = {0.0f, 0.0f, 0.0f};
  r.qex = qex; r.qin = qin;
  r.sex = sex; r.sin = sin_;
  r.pex = pex; r.pin = pin;
  r.Tex = Tex; r.Tin = Tin;
  return r;
}

// Kernel 1: per-chunk aggregates. 2 INDEPENDENT waves per 128-thread block,
// 6 KB wave-private LDS each, no barriers (per-wave vmcnt wait).
__global__ __launch_bounds__(128) void k_agg(
    const float* __restrict__ dtp, const float* __restrict__ gyp,
    const float* __restrict__ acp, const float* __restrict__ gtp,
    St* __restrict__ aggs)
{
  __shared__ __align__(16) float lds[2*WAVE_F];   // 12 KB
  const int tid = threadIdx.x;
  const int t = tid & 63, wv = tid >> 6;
  const int cid = blockIdx.x*2 + wv;
  const size_t base = (size_t)cid * WCHUNK;
  const int wbF = wv * WAVE_F, wbB = wv * 6144;

  stage_wave(lds, wbB, t, gyp, acp, base);
  float4 dt4 = ((const float4*)(dtp + base))[t];
  const float4* ggt = (const float4*)(gtp + base*4);
  float4 gq4[4];
  #pragma unroll
  for (int i = 0; i < 4; ++i) gq4[i] = ggt[4*t + i];   // 64 B contiguous/lane

  asm volatile("s_waitcnt vmcnt(0)" ::: "memory");      // per-wave DMA drain

  Compressed C;
  Seg s = build_slim(lds, wbF, t, dt4, gq4, C);
  ScanRes R = wave_split_scan(t, s);

  if (t == 63) {
    St a;
    a.q = R.qin; a.s = R.sin; a.p = R.pin; a.T = R.Tin; a.pad = 0.0f;
    aggs[cid] = a;
  }
}

// Kernel 2: exclusive chunk prefixes. One wave per batch row; cpb in
// 64-wide windows with carry. (Unchanged.)
__global__ __launch_bounds__(64) void k_pref(
    const St* __restrict__ aggs, const float* __restrict__ irp,
    float* __restrict__ prefb, int cpb)
{
  const int b = blockIdx.x;
  const int lane = threadIdx.x & 63;

  St carry = identity_st();
  carry.q = { irp[b*4+0], irp[b*4+1], irp[b*4+2], irp[b*4+3] };

  const int nw = (cpb + 63) >> 6;
  for (int w = 0; w < nw; ++w) {
    const int idx = (w << 6) + lane;
    St A = identity_st();
    if (idx < cpb) A = aggs[(size_t)b*cpb + idx];
    #pragma unroll
    for (int d = 1; d < 64; d <<= 1) {
      St o = shfl_up_st(A, d);
      if (lane >= d) A = combine(o, A);
    }
    St ex = shfl_up_st(A, 1);
    St P = (lane == 0) ? carry : combine(carry, ex);
    if (idx < cpb) {
      float4* pp = (float4*)(prefb + ((size_t)b*cpb + idx)*12);
      pp[0] = make_float4(P.q.x, P.q.y, P.q.z, P.q.w);
      pp[1] = make_float4(P.s.x, P.s.y, P.s.z, P.p.x);
      pp[2] = make_float4(P.p.y, P.p.z, P.T, 0.0f);
    }
    carry = combine(carry, bcast_st(A, 63));
  }
}

// Kernel 3: emit. 2 INDEPENDENT waves per block, no barriers. rot stored
// DIRECT (4 contiguous float4/lane); vel/pos restaged dense via the
// wave-private gy/ac regions (in-wave lgkmcnt orders the RAW/WAR).
__global__ __launch_bounds__(128) void k_emit(
    const float* __restrict__ dtp, const float* __restrict__ gyp,
    const float* __restrict__ acp, const float* __restrict__ gtp,
    const float* __restrict__ prefb,
    const float* __restrict__ ivp, const float* __restrict__ ipp,
    float* __restrict__ out, int F, int cpb, int B)
{
  __shared__ __align__(16) float lds[2*WAVE_F];   // 12 KB
  const int tid = threadIdx.x;
  const int t = tid & 63, wv = tid >> 6;
  const int cid = blockIdx.x*2 + wv;
  const int b = cid / cpb;
  const size_t base = (size_t)cid * WCHUNK;
  const int wbF = wv * WAVE_F, wbB = wv * 6144;

  // uniform loads first: wave prefix + per-batch vectors
  Q4 Pq; V3 Ps, Pp; float PT;
  {
    const float4* pp = (const float4*)(prefb + (size_t)cid*12);
    float4 a = pp[0], bb = pp[1], cc = pp[2];
    Pq = {a.x, a.y, a.z, a.w};
    Ps = {bb.x, bb.y, bb.z};
    Pp = {bb.w, cc.x, cc.y};
    PT = cc.z;
  }
  V3 iv = { ivp[b*3+0], ivp[b*3+1], ivp[b*3+2] };
  V3 ip = { ipp[b*3+0], ipp[b*3+1], ipp[b*3+2] };

  stage_wave(lds, wbB, t, gyp, acp, base);
  float4 dt4 = ((const float4*)(dtp + base))[t];
  const float4* ggt = (const float4*)(gtp + base*4);
  float4 gq4[4];
  #pragma unroll
  for (int i = 0; i < 4; ++i) gq4[i] = ggt[4*t + i];

  asm volatile("s_waitcnt vmcnt(0)" ::: "memory");      // per-wave DMA drain

  Compressed C;
  Seg s = build_slim(lds, wbF, t, dt4, gq4, C);
  ScanRes S = wave_split_scan(t, s);

  // apply chunk prefix to this lane's exclusive state: X = P ∘ ex
  Q4 Xq = qmul(Pq, S.qex);
  V3 rs = qrot(Pq, S.sex);
  V3 Xs = { Ps.x + rs.x, Ps.y + rs.y, Ps.z + rs.z };
  V3 rp = qrot(Pq, S.pex);
  V3 Xp = { Pp.x + Ps.x*S.Tex + rp.x, Pp.y + Ps.y*S.Tex + rp.y,
            Pp.z + Ps.z*S.Tex + rp.z };
  float XT = PT + S.Tex;

  // split emit: rot direct to global; vel/pos into LDS then dense stores
  const size_t BF = (size_t)B * (size_t)F;
  float4* grot = (float4*)out + base;
  {
    Q4 qr = Xq; V3 sr = Xs; V3 pr = Xp; float Tr = XT;
    float velb[12], posb[12];
    #pragma unroll
    for (int i = 0; i < SEQ; ++i) {
      float qx = C.cq[3*i], qy = C.cq[3*i+1], qz = C.cq[3*i+2];
      Q4 eq = { qx, qy, qz, sqrtf(fmaxf(1.0f - qx*qx - qy*qy - qz*qz, 0.0f)) };
      V3 es = { C.cs[3*i], C.cs[3*i+1], C.cs[3*i+2] };
      float dt = C.cdt[i], h = 0.5f*dt;
      V3 vv = qrot(qr, es);
      V3 pn = { pr.x + sr.x*dt + vv.x*h,
                pr.y + sr.y*dt + vv.y*h,
                pr.z + sr.z*dt + vv.z*h };
      V3 sn = { sr.x + vv.x, sr.y + vv.y, sr.z + vv.z };
      Q4 qn = qmul(qr, eq);
      float Tn = Tr + dt;
      grot[4*t + i] = make_float4(qn.x, qn.y, qn.z, qn.w);  // 64 B/lane
      velb[3*i+0] = iv.x + sn.x;
      velb[3*i+1] = iv.y + sn.y;
      velb[3*i+2] = iv.z + sn.z;
      posb[3*i+0] = ip.x + iv.x*Tn + pn.x;
      posb[3*i+1] = ip.y + iv.y*Tn + pn.y;
      posb[3*i+2] = ip.z + iv.z*Tn + pn.z;
      qr = qn; sr = sn; pr = pn; Tr = Tn;
    }
    // overwrite gy/ac regions (in-wave lgkmcnt orders vs build's reads)
    #pragma unroll
    for (int j = 0; j < 3; ++j) L4(lds, wbF + 12*t + 4*j) = ((float4*)velb)[j];
    #pragma unroll
    for (int j = 0; j < 3; ++j) L4(lds, wbF + AC_REL + 12*t + 4*j) = ((float4*)posb)[j];
  }

  // dense stores (cross-lane within the wave: ordered by lgkmcnt waits)
  float4* gvel = (float4*)(out + BF*4 + base*3);
  float4* gpos = (float4*)(out + BF*7 + base*3);
  #pragma unroll
  for (int k = 0; k < 3; ++k) gvel[t + 64*k] = L4(lds, wbF + 4*(t + 64*k));
  #pragma unroll
  for (int k = 0; k < 3; ++k) gpos[t + 64*k] = L4(lds, wbF + AC_REL + 4*(t + 64*k));
}

} // namespace

extern "C" void kernel_launch(void* const* d_in, const int* in_sizes, int n_in,
                              void* d_out, int out_size, void* d_ws, size_t ws_size,
                              hipStream_t stream)
{
  (void)n_in; (void)out_size; (void)ws_size;

  const float* dtp = (const float*)d_in[0];
  const float* gyp = (const float*)d_in[1];
  const float* acp = (const float*)d_in[2];
  const float* gtp = (const float*)d_in[3];
  const float* irp = (const float*)d_in[4];
  const float* ivp = (const float*)d_in[5];
  const float* ipp = (const float*)d_in[6];
  float* out = (float*)d_out;

  const int B   = in_sizes[4] / 4;    // init_rot has B*4 elements
  const int F   = in_sizes[0] / B;    // dt has B*F elements
  const int cpb = F / WCHUNK;         // 128 for F=32768
  const int nchunk = B * cpb;         // 8192 (even)

  St*    aggs  = (St*)d_ws;
  float* prefb = (float*)((char*)d_ws + (size_t)nchunk * sizeof(St));

  k_agg <<<nchunk/2, 128, 0, stream>>>(dtp, gyp, acp, gtp, aggs);
  k_pref<<<B,         64, 0, stream>>>(aggs, irp, prefb, cpb);
  k_emit<<<nchunk/2, 128, 0, stream>>>(dtp, gyp, acp, gtp, prefb, ivp, ipp,
                                       out, F, cpb, B);
}